// Round 4
// baseline (195.098 us; speedup 1.0000x reference)
//
#include <hip/hip_runtime.h>

// OptimizedLinear: out = x@W^T + bias - lr[:,None]*(x@G^T + bias_grad)
// B=4096, IN=OUT=2048, fp32 in/out. bf16 MFMA fused dual-accumulator GEMM.
// Round 4: 128x64 tile (was 128x128), grid 32x32=1024 blocks, 4 blocks/CU
// (launch_bounds(256,4)) — doubles inter-block overlap to hide the barrier
// drain that pinned the 128x128 version at ~83.8us (2 blocks/CU, Occ 20%).
// A-panel stays 128 rows so dual-acc amortization of the x operand holds.
// Lessons carried: hipLaunchCooperativeKernel silently fails under this
// harness's graph capture (round 3); SQ_LDS_BANK_CONFLICT == 8 per
// global_load_lds_dwordx4 is intrinsic write-beat serialization, not a
// tunable conflict (rounds 1-2).

typedef unsigned short ushort_t;
typedef __attribute__((ext_vector_type(8))) short short8;       // 8 bf16 = 4 VGPR
typedef __attribute__((ext_vector_type(8))) unsigned short ushort8;
typedef __attribute__((ext_vector_type(4))) float f32x4;

#define GPTR(p) ((const __attribute__((address_space(1))) void*)(p))
#define LPTR(p) ((__attribute__((address_space(3))) void*)(p))

static constexpr int Kdim = 2048;
static constexpr int Ndim = 2048;

__device__ __forceinline__ unsigned short f2bf(float f) {
    union { float f; unsigned u; } c; c.f = f;
    unsigned u = c.u;
    unsigned r = (u + 0x7fffu + ((u >> 16) & 1u)) >> 16;  // RNE
    return (unsigned short)r;
}

// One launch converts x (uX ushort8-units), W (uW), G (uW). Unit = 8 elems.
__global__ void cvt_all_kernel(const float* __restrict__ x,
                               const float* __restrict__ W,
                               const float* __restrict__ G,
                               ushort_t* __restrict__ xb,
                               ushort_t* __restrict__ wb,
                               ushort_t* __restrict__ gb,
                               int uX, int uW) {
    int u = blockIdx.x * blockDim.x + threadIdx.x;
    const float* src; ushort_t* dst;
    if (u < uX)            { src = x; dst = xb; }
    else if (u < uX + uW)  { src = W; dst = wb; u -= uX; }
    else                   { src = G; dst = gb; u -= uX + uW; }
    int i = u * 8;
    float4 a = *(const float4*)(src + i);
    float4 b = *(const float4*)(src + i + 4);
    ushort8 r;
    r[0] = f2bf(a.x); r[1] = f2bf(a.y); r[2] = f2bf(a.z); r[3] = f2bf(a.w);
    r[4] = f2bf(b.x); r[5] = f2bf(b.y); r[6] = f2bf(b.z); r[7] = f2bf(b.w);
    *(ushort8*)(dst + i) = r;
}

// ---- fused dual GEMM, 128(M) x 64(N) C-tile ----
// 256 threads = 4 waves in a 2x2 arrangement; each wave owns 64x32 =
// 4(m) x 2(n) MFMA tiles, dual accumulators (base & pert).
// LDS tiles: As 128x32 (2 staging issues), Ws/Gs 64x32 (1 issue each).
// Granule swizzle: slot s holds (row = s>>2, q = (s&3) ^ (row&3)); applied
// on the GLOBAL fetch address (LDS dst is HW-forced to base + lane*16).
__global__ __launch_bounds__(256, 4) void fused_gemm_kernel(
    const ushort_t* __restrict__ xb,   // [4096, 2048] bf16
    const ushort_t* __restrict__ wb,   // [2048, 2048] bf16
    const ushort_t* __restrict__ gb,   // [2048, 2048] bf16
    const float* __restrict__ bias,    // [2048]
    const float* __restrict__ bgrad,   // [2048]
    const float* __restrict__ lr,      // [4096]
    float* __restrict__ out)           // [4096, 2048] fp32
{
    __shared__ ushort_t As[128 * 32];  // 8 KB
    __shared__ ushort_t Ws[64 * 32];   // 4 KB
    __shared__ ushort_t Gs[64 * 32];   // 4 KB

    const int t    = threadIdx.x;
    const int wave = t >> 6;
    const int lane = t & 63;
    const int wm   = (wave >> 1) * 64;   // 0 or 64 within M=128
    const int wn   = (wave & 1) * 32;    // 0 or 32 within N=64
    const int bx   = blockIdx.x;         // N tile (0..31)
    const int by   = blockIdx.y;         // M tile (0..31)

    f32x4 accB[4][2] = {};
    f32x4 accP[4][2] = {};

    // staging slots: A issue0 s=t, A issue1 s=256+t, W s=t, G s=t
    const int s0 = t,       rowA0 = s0 >> 2, kkA0 = (((s0 & 3) ^ (rowA0 & 3)) * 8);
    const int s1 = 256 + t, rowA1 = s1 >> 2, kkA1 = (((s1 & 3) ^ (rowA1 & 3)) * 8);
    // W/G: same formula as s0 (rows 0..63)

    const size_t aBase = (size_t)(by * 128);
    const size_t wBase = (size_t)(bx * 64);

    const ushort_t* ga0 = xb + (aBase + rowA0) * Kdim + kkA0;
    const ushort_t* ga1 = xb + (aBase + rowA1) * Kdim + kkA1;
    const ushort_t* gw0 = wb + (wBase + rowA0) * Kdim + kkA0;
    const ushort_t* gg0 = gb + (wBase + rowA0) * Kdim + kkA0;

    // LDS dst: wave-uniform base + lane*16B
    ushort_t* lA0 = As + (wave * 64) * 8;
    ushort_t* lA1 = As + (256 + wave * 64) * 8;
    ushort_t* lW0 = Ws + (wave * 64) * 8;
    ushort_t* lG0 = Gs + (wave * 64) * 8;

    const int fr = lane & 15;                         // fragment row
    const int kc = (((lane >> 4) ^ (fr & 3)) * 8);    // swizzled k-granule offset

    for (int k0 = 0; k0 < Kdim; k0 += 32) {
        __builtin_amdgcn_global_load_lds(GPTR(ga0 + k0), LPTR(lA0), 16, 0, 0);
        __builtin_amdgcn_global_load_lds(GPTR(ga1 + k0), LPTR(lA1), 16, 0, 0);
        __builtin_amdgcn_global_load_lds(GPTR(gw0 + k0), LPTR(lW0), 16, 0, 0);
        __builtin_amdgcn_global_load_lds(GPTR(gg0 + k0), LPTR(lG0), 16, 0, 0);
        __syncthreads();

        short8 af[4], wf[2], gf[2];
#pragma unroll
        for (int mt = 0; mt < 4; ++mt)
            af[mt] = *(const short8*)(As + (wm + mt * 16 + fr) * 32 + kc);
#pragma unroll
        for (int nt = 0; nt < 2; ++nt) {
            wf[nt] = *(const short8*)(Ws + (wn + nt * 16 + fr) * 32 + kc);
            gf[nt] = *(const short8*)(Gs + (wn + nt * 16 + fr) * 32 + kc);
        }
#pragma unroll
        for (int mt = 0; mt < 4; ++mt)
#pragma unroll
            for (int nt = 0; nt < 2; ++nt) {
                accB[mt][nt] = __builtin_amdgcn_mfma_f32_16x16x32_bf16(
                    af[mt], wf[nt], accB[mt][nt], 0, 0, 0);
                accP[mt][nt] = __builtin_amdgcn_mfma_f32_16x16x32_bf16(
                    af[mt], gf[nt], accP[mt][nt], 0, 0, 0);
            }
        __syncthreads();
    }

    // epilogue: out = base + bias[n] - lr[m]*(pert + bgrad[n])
    // C/D layout: col = lane&15, row = (lane>>4)*4 + reg
    const int col  = lane & 15;
    const int quad = lane >> 4;
    const int gmb  = by * 128 + wm;
    const int gnb  = bx * 64 + wn;

    float lrv[4][4];
#pragma unroll
    for (int mt = 0; mt < 4; ++mt)
#pragma unroll
        for (int i = 0; i < 4; ++i)
            lrv[mt][i] = lr[gmb + mt * 16 + quad * 4 + i];

#pragma unroll
    for (int nt = 0; nt < 2; ++nt) {
        const int gn = gnb + nt * 16 + col;
        const float bn = bias[gn];
        const float bg = bgrad[gn];
#pragma unroll
        for (int mt = 0; mt < 4; ++mt) {
#pragma unroll
            for (int i = 0; i < 4; ++i) {
                const int gm = gmb + mt * 16 + quad * 4 + i;
                float v = accB[mt][nt][i] + bn - lrv[mt][i] * (accP[mt][nt][i] + bg);
                __builtin_nontemporal_store(v, out + (size_t)gm * Ndim + gn);
            }
        }
    }
}

extern "C" void kernel_launch(void* const* d_in, const int* in_sizes, int n_in,
                              void* d_out, int out_size, void* d_ws, size_t ws_size,
                              hipStream_t stream) {
    const float* x     = (const float*)d_in[0];  // [4096, 2048]
    const float* W     = (const float*)d_in[1];  // [2048, 2048]
    const float* bias  = (const float*)d_in[2];  // [2048]
    const float* G     = (const float*)d_in[3];  // [2048, 2048]
    const float* bgrad = (const float*)d_in[4];  // [2048]
    const float* lr    = (const float*)d_in[5];  // [4096]
    float* out = (float*)d_out;

    const int nX = 4096 * 2048;
    const int nW = 2048 * 2048;

    ushort_t* xb = (ushort_t*)d_ws;
    ushort_t* wb = xb + nX;
    ushort_t* gb = wb + nW;

    const int uX = nX / 8, uW = nW / 8;
    const int totalU = uX + 2 * uW;               // 2,097,152
    cvt_all_kernel<<<totalU / 256, 256, 0, stream>>>(x, W, G, xb, wb, gb, uX, uW);

    dim3 grid(32, 32);   // N tiles x M tiles = 1024 blocks = 4/CU
    fused_gemm_kernel<<<grid, 256, 0, stream>>>(xb, wb, gb, bias, bgrad, lr, out);
}